// Round 4
// baseline (149.279 us; speedup 1.0000x reference)
//
#include <hip/hip_runtime.h>

// N=4096 rows, D=128 in-dim, P=128 pe-dim, H=256 hidden.
// out: (N, 129) fp32, col 0 = ones, col j+1 = x[:,j] * (1 + g_j)
//
//   base[n][h] = sum_i x[n][i]*W1[i][h] + b1[h]          (kernel 1 -> d_ws)
//   g = sum_h relu(base[n][h] + W1[128+j][h] - x[n][j]*W1[j][h]) * W2[h] + b2
//   out[n][1+j] = x[n][j] * (1 + g)

#define NROWS 4096
#define DIN   128
#define HDIM  256
#define JCH   8

// ---------------- Kernel 1: base = x @ W1[:128] + b1 ----------------
// grid (128,4), block 256. Tile 32 rows x 64 h, full K=128 of x staged
// transposed in LDS (stride 36 keeps 16B alignment for ds_read_b128).
__global__ __launch_bounds__(256) void nimo_base(
    const float* __restrict__ x, const float* __restrict__ W1,
    const float* __restrict__ b1, float* __restrict__ baseb)
{
    __shared__ float xs[DIN * 36];
    const int tid  = threadIdx.x;
    const int row0 = blockIdx.x * 32;
    const int h0   = blockIdx.y * 64;

    {
        const int bidx = tid * 16;
        const int r = bidx >> 7;
        const int c = bidx & 127;
        #pragma unroll
        for (int u = 0; u < 4; ++u) {
            const float4 v = *(const float4*)(x + (size_t)(row0 + r) * DIN + c + u * 4);
            xs[(c + u * 4 + 0) * 36 + r] = v.x;
            xs[(c + u * 4 + 1) * 36 + r] = v.y;
            xs[(c + u * 4 + 2) * 36 + r] = v.z;
            xs[(c + u * 4 + 3) * 36 + r] = v.w;
        }
    }
    __syncthreads();

    const int tx = tid & 31;
    const int ty = tid >> 5;
    const float* __restrict__ wcol = W1 + h0 + tx * 2;

    float2 acc[4];
    #pragma unroll
    for (int u = 0; u < 4; ++u) { acc[u].x = 0.f; acc[u].y = 0.f; }

    #pragma unroll 8
    for (int k = 0; k < DIN; ++k) {
        const float2 w  = *(const float2*)(wcol + (size_t)k * HDIM);
        const float4 xv = *(const float4*)(&xs[k * 36 + ty * 4]);
        acc[0].x = fmaf(xv.x, w.x, acc[0].x); acc[0].y = fmaf(xv.x, w.y, acc[0].y);
        acc[1].x = fmaf(xv.y, w.x, acc[1].x); acc[1].y = fmaf(xv.y, w.y, acc[1].y);
        acc[2].x = fmaf(xv.z, w.x, acc[2].x); acc[2].y = fmaf(xv.z, w.y, acc[2].y);
        acc[3].x = fmaf(xv.w, w.x, acc[3].x); acc[3].y = fmaf(xv.w, w.y, acc[3].y);
    }

    const float2 bv = *(const float2*)(b1 + h0 + tx * 2);
    #pragma unroll
    for (int u = 0; u < 4; ++u) {
        float2 o; o.x = acc[u].x + bv.x; o.y = acc[u].y + bv.y;
        *(float2*)(baseb + (size_t)(row0 + ty * 4 + u) * HDIM + h0 + tx * 2) = o;
    }
}

// ---------------- Kernel 2: masked-MLP evaluation ----------------
// grid (64, 16), block 512 = 8 waves. Wave q owns h-chunk [q*32, q*32+32);
// lane = row (r = tid&63). Per-lane register-resident: bb[32], w2r[32].
// W1 j-slab (8 j x 256 h, wa+wp) staged in LDS once per block; inner loop
// reads it with wave-uniform ds_read_b128 broadcasts (no global mem, no
// compiler-dependent scalarization). 8-way h-partials combined via LDS.
// LDS: sa 8K + sp 8K + xs 2.25K + part 16.5K = 35.9 KB (< 64 KB cap).
__global__ __launch_bounds__(512, 4) void nimo_main(
    const float* __restrict__ x, const float* __restrict__ W1,
    const float* __restrict__ W2, const float* __restrict__ b2,
    const float* __restrict__ baseb, float* __restrict__ out)
{
    __shared__ float sa[JCH][HDIM];        // W1[j0+jj][h]
    __shared__ float sp[JCH][HDIM];        // W1[128+j0+jj][h]
    __shared__ float xs[64][JCH + 1];      // x[row0+r][j0+jj], stride 9
    __shared__ float part[8][JCH][66];     // per-wave h-partials

    const int tid  = threadIdx.x;
    const int r    = tid & 63;
    const int q    = tid >> 6;             // wave id 0..7
    const int row0 = blockIdx.x * 64;
    const int row  = row0 + r;
    const int j0   = blockIdx.y * JCH;
    const int h0   = q * 32;

    // ---- stage W1 slab (coalesced float4) + x tile ----
    {
        const float4* wsrc = (const float4*)(W1 + (size_t)j0 * HDIM);
        const float4* psrc = (const float4*)(W1 + (size_t)(DIN + j0) * HDIM);
        ((float4*)&sa[0][0])[tid] = wsrc[tid];   // 512 float4 = 8 j rows x 256 h
        ((float4*)&sp[0][0])[tid] = psrc[tid];
        const int xr = tid >> 3;               // 0..63
        const int xc = tid & 7;                // 0..7
        xs[xr][xc] = x[(size_t)(row0 + xr) * DIN + j0 + xc];
    }

    // ---- per-lane resident data ----
    float bb[32], w2r[32];
    {
        const float4* bp = (const float4*)(baseb + (size_t)row * HDIM + h0);
        const float4* wp2 = (const float4*)(W2 + h0);
        #pragma unroll
        for (int u = 0; u < 8; ++u) { ((float4*)bb)[u] = bp[u]; ((float4*)w2r)[u] = wp2[u]; }
    }
    __syncthreads();

    // ---- j-loop: pure VALU + wave-uniform LDS broadcast ----
    for (int jj = 0; jj < JCH; ++jj) {
        const float xj = xs[r][jj];
        const float* wa = &sa[jj][h0];
        const float* wp = &sp[jj][h0];
        float acc = 0.f;
        #pragma unroll
        for (int u = 0; u < 8; ++u) {
            const float4 a4 = *(const float4*)(wa + u * 4);   // ds_read_b128, uniform
            const float4 p4 = *(const float4*)(wp + u * 4);   // ds_read_b128, uniform
            float t;
            t = fmaf(-xj, a4.x, bb[u*4+0] + p4.x); t = fmaxf(t, 0.f); acc = fmaf(t, w2r[u*4+0], acc);
            t = fmaf(-xj, a4.y, bb[u*4+1] + p4.y); t = fmaxf(t, 0.f); acc = fmaf(t, w2r[u*4+1], acc);
            t = fmaf(-xj, a4.z, bb[u*4+2] + p4.z); t = fmaxf(t, 0.f); acc = fmaf(t, w2r[u*4+2], acc);
            t = fmaf(-xj, a4.w, bb[u*4+3] + p4.w); t = fmaxf(t, 0.f); acc = fmaf(t, w2r[u*4+3], acc);
        }
        part[q][jj][r] = acc;
    }
    __syncthreads();

    // ---- combine 8 h-partials, write out ----
    const float b2s = b2[0];
    if (blockIdx.y == 0 && tid < 64) out[(size_t)(row0 + tid) * 129] = 1.0f;

    {
        const int rr = tid >> 3;               // 0..63
        const int jj = tid & 7;                // 0..7
        float g = 0.f;
        #pragma unroll
        for (int qq = 0; qq < 8; ++qq) g += part[qq][jj][rr];
        const float xv = xs[rr][jj];
        out[(size_t)(row0 + rr) * 129 + 1 + j0 + jj] = xv * (1.0f + g + b2s);
    }
}

extern "C" void kernel_launch(void* const* d_in, const int* in_sizes, int n_in,
                              void* d_out, int out_size, void* d_ws, size_t ws_size,
                              hipStream_t stream) {
    const float* x  = (const float*)d_in[0];   // 4096*128
    const float* W1 = (const float*)d_in[1];   // 256*256
    const float* b1 = (const float*)d_in[2];   // 256
    const float* W2 = (const float*)d_in[3];   // 256
    const float* b2 = (const float*)d_in[4];   // 1
    float* out = (float*)d_out;                // 4096*129
    float* baseb = (float*)d_ws;               // 4096*256 fp32 = 4 MB scratch

    nimo_base<<<dim3(NROWS / 32, HDIM / 64), 256, 0, stream>>>(x, W1, b1, baseb);
    nimo_main<<<dim3(NROWS / 64, DIN / JCH), 512, 0, stream>>>(x, W1, W2, b2, baseb, out);
}

// Round 5
// 87.866 us; speedup vs baseline: 1.6989x; 1.6989x over previous
//
#include <hip/hip_runtime.h>

// N=4096 rows, D=128 in-dim, P=128 pe-dim, H=256 hidden.
// out: (N, 129) fp32, col 0 = ones, col j+1 = x[:,j] * (1 + g_j)
//
//   base[n][h] = sum_i x[n][i]*W1[i][h] + b1[h]          (kernel 1 -> d_ws)
//   g = sum_h relu(base[n][h] + W1[128+j][h] - x[n][j]*W1[j][h]) * W2[h] + b2
//   out[n][1+j] = x[n][j] * (1 + g)

#define NROWS 4096
#define DIN   128
#define HDIM  256
#define JCH   8

typedef float sfloat16 __attribute__((ext_vector_type(16)));

// ---------------- Kernel 1: base = x @ W1[:128] + b1 ----------------
// grid (128,4), block 256. Tile 32 rows x 64 h, K=128 of x transposed in LDS.
__global__ __launch_bounds__(256) void nimo_base(
    const float* __restrict__ x, const float* __restrict__ W1,
    const float* __restrict__ b1, float* __restrict__ baseb)
{
    __shared__ float xs[DIN * 36];
    const int tid  = threadIdx.x;
    const int row0 = blockIdx.x * 32;
    const int h0   = blockIdx.y * 64;

    {
        const int bidx = tid * 16;
        const int r = bidx >> 7;
        const int c = bidx & 127;
        #pragma unroll
        for (int u = 0; u < 4; ++u) {
            const float4 v = *(const float4*)(x + (size_t)(row0 + r) * DIN + c + u * 4);
            xs[(c + u * 4 + 0) * 36 + r] = v.x;
            xs[(c + u * 4 + 1) * 36 + r] = v.y;
            xs[(c + u * 4 + 2) * 36 + r] = v.z;
            xs[(c + u * 4 + 3) * 36 + r] = v.w;
        }
    }
    __syncthreads();

    const int tx = tid & 31;
    const int ty = tid >> 5;
    const float* __restrict__ wcol = W1 + h0 + tx * 2;

    float2 acc[4];
    #pragma unroll
    for (int u = 0; u < 4; ++u) { acc[u].x = 0.f; acc[u].y = 0.f; }

    #pragma unroll 8
    for (int k = 0; k < DIN; ++k) {
        const float2 w  = *(const float2*)(wcol + (size_t)k * HDIM);
        const float4 xv = *(const float4*)(&xs[k * 36 + ty * 4]);
        acc[0].x = fmaf(xv.x, w.x, acc[0].x); acc[0].y = fmaf(xv.x, w.y, acc[0].y);
        acc[1].x = fmaf(xv.y, w.x, acc[1].x); acc[1].y = fmaf(xv.y, w.y, acc[1].y);
        acc[2].x = fmaf(xv.z, w.x, acc[2].x); acc[2].y = fmaf(xv.z, w.y, acc[2].y);
        acc[3].x = fmaf(xv.w, w.x, acc[3].x); acc[3].y = fmaf(xv.w, w.y, acc[3].y);
    }

    const float2 bv = *(const float2*)(b1 + h0 + tx * 2);
    #pragma unroll
    for (int u = 0; u < 4; ++u) {
        float2 o; o.x = acc[u].x + bv.x; o.y = acc[u].y + bv.y;
        *(float2*)(baseb + (size_t)(row0 + ty * 4 + u) * HDIM + h0 + tx * 2) = o;
    }
}

// ---------------- Kernel 2: masked-MLP evaluation ----------------
// grid (64, 16), block 1024 = 16 waves. Wave q owns h-chunk [q*16, q*16+16);
// lane = row (r = tid&63). Per-lane REGISTER-resident bb[16], w2r[16]
// (constant-index access only — no address casts -> no scratch spill).
// W1 rows are wave-uniform: forced into SGPRs via inline-asm s_load_dwordx16
// (readfirstlane'd uniform address). Inner loop: 64 pure-VALU ops, each with
// <=1 SGPR operand (legal), zero vector-memory, zero LDS.
// 16-way h-partials combined once via LDS. LDS total ~36 KB.
__global__ __launch_bounds__(1024, 8) void nimo_main(
    const float* __restrict__ x, const float* __restrict__ W1,
    const float* __restrict__ W2, const float* __restrict__ b2,
    const float* __restrict__ baseb, float* __restrict__ out)
{
    __shared__ float xs[64][JCH + 1];      // x[row0+r][j0+jj]
    __shared__ float part[16][JCH][66];    // per-wave h-partials

    const int tid  = threadIdx.x;
    const int r    = tid & 63;
    const int q    = tid >> 6;             // wave id 0..15
    const int row0 = blockIdx.x * 64;
    const int row  = row0 + r;
    const int j0   = blockIdx.y * JCH;
    const int h0   = q * 16;

    // stage x tile (64 rows x JCH cols)
    if (tid < 512) {
        const int xr = tid >> 3;
        const int xc = tid & 7;
        xs[xr][xc] = x[(size_t)(row0 + xr) * DIN + j0 + xc];
    }

    // per-lane resident data: constant-index scalar writes keep these in VGPRs
    float bb[16], w2r[16];
    {
        const float4* bp  = (const float4*)(baseb + (size_t)row * HDIM + h0);
        const float4* wp2 = (const float4*)(W2 + h0);
        #pragma unroll
        for (int u = 0; u < 4; ++u) {
            const float4 v = bp[u];
            bb[u * 4 + 0] = v.x; bb[u * 4 + 1] = v.y;
            bb[u * 4 + 2] = v.z; bb[u * 4 + 3] = v.w;
            const float4 w = wp2[u];
            w2r[u * 4 + 0] = w.x; w2r[u * 4 + 1] = w.y;
            w2r[u * 4 + 2] = w.z; w2r[u * 4 + 3] = w.w;
        }
    }
    __syncthreads();

    for (int jj = 0; jj < JCH; ++jj) {
        const float xj = xs[r][jj];
        unsigned off = (unsigned)(((j0 + jj) * HDIM + h0) * 4);
        off = __builtin_amdgcn_readfirstlane(off);   // provably wave-uniform
        sfloat16 wa, wp;
        asm volatile(
            "s_load_dwordx16 %0, %2, 0x0\n\t"
            "s_load_dwordx16 %1, %2, 0x20000\n\t"    // +128*256*4 B -> W1[128+j]
            "s_waitcnt lgkmcnt(0)"
            : "=s"(wa), "=s"(wp)
            : "s"((unsigned long long)(uintptr_t)W1 + off));

        float acc = 0.f;
        #pragma unroll
        for (int h = 0; h < 16; ++h) {
            float t = bb[h] + wp[h];          // v_add (1 sgpr src)
            t = fmaf(-xj, wa[h], t);          // v_fma (1 sgpr src)
            t = fmaxf(t, 0.f);                // v_max
            acc = fmaf(t, w2r[h], acc);       // v_fma
        }
        part[q][jj][r] = acc;                 // lane=r consecutive: conflict-free
    }
    __syncthreads();

    const float b2s = b2[0];
    if (blockIdx.y == 0 && tid < 64) out[(size_t)(row0 + tid) * 129] = 1.0f;

    if (tid < 512) {
        const int rr = tid >> 3;              // 0..63
        const int jj = tid & 7;               // 0..7
        float g = 0.f;
        #pragma unroll
        for (int qq = 0; qq < 16; ++qq) g += part[qq][jj][rr];
        const float xv = xs[rr][jj];
        out[(size_t)(row0 + rr) * 129 + 1 + j0 + jj] = xv * (1.0f + g + b2s);
    }
}

extern "C" void kernel_launch(void* const* d_in, const int* in_sizes, int n_in,
                              void* d_out, int out_size, void* d_ws, size_t ws_size,
                              hipStream_t stream) {
    const float* x  = (const float*)d_in[0];   // 4096*128
    const float* W1 = (const float*)d_in[1];   // 256*256
    const float* b1 = (const float*)d_in[2];   // 256
    const float* W2 = (const float*)d_in[3];   // 256
    const float* b2 = (const float*)d_in[4];   // 1
    float* out = (float*)d_out;                // 4096*129
    float* baseb = (float*)d_ws;               // 4096*256 fp32 = 4 MB scratch

    nimo_base<<<dim3(NROWS / 32, HDIM / 64), 256, 0, stream>>>(x, W1, b1, baseb);
    nimo_main<<<dim3(NROWS / 64, DIN / JCH), 1024, 0, stream>>>(x, W1, W2, b2, baseb, out);
}